// Round 10
// baseline (3305.144 us; speedup 1.0000x reference)
//
#include <hip/hip_runtime.h>

// ---------------------------------------------------------------------------
// RWKV-7 MoE FFN, MI355X (gfx950). bf16 MFMA + top-2 sparse expert dispatch.
// r10: gemm256 rebuilt as an 8-phase counted-vmcnt pipeline (T3+T4+T5):
//   BM=256 BN=128 BK=64, 8 waves (4M x 2N), LDS A=[buf][mh][wr][32][128B],
//   B=[buf][nh][wc][32][128B]; phases = C-quadrants (mh,nh) x K=64;
//   half-tile staging staggered p2/p3/p0; vmcnt(6) at p0/p3 ends (0 at tail);
//   raw s_barrier (no vmcnt drain), setprio around MFMA.
// Everything else identical to the r9 structure (passed, absmax 0.25).
// Shapes fixed: B=4 T=2048 C=2048 H=8192 R=64 E=4, topk=2.
// ---------------------------------------------------------------------------

#define DEV_INLINE __device__ __forceinline__

typedef __attribute__((ext_vector_type(8))) short bf16x8;
typedef __attribute__((ext_vector_type(4))) float f32x4;

DEV_INLINE unsigned short f2bf(float f) {
  union { float f; unsigned int u; } v; v.f = f;
  unsigned int u = v.u;
  unsigned int r = (u + 0x7FFFu + ((u >> 16) & 1u)) >> 16;  // RTNE
  return (unsigned short)r;
}
DEV_INLINE float bf2f(unsigned short s) {
  union { unsigned int u; float f; } v; v.u = ((unsigned int)s) << 16;
  return v.f;
}

// ---------------------------------------------------------------------------
__global__ __launch_bounds__(256) void prep_kernel(
    const float* __restrict__ x, const float* __restrict__ x_prev,
    const float* __restrict__ x_k, unsigned short* __restrict__ h, int n0) {
  const int idx = blockIdx.x * 256 + threadIdx.x;
  const int c4 = idx & 511;
  const int gn = n0 + (idx >> 9);
  const int t  = gn & 2047;
  const int b  = gn >> 11;
  const float4 cur = ((const float4*)x)[(size_t)gn * 512 + c4];
  const float4 prv = (t == 0) ? ((const float4*)x_prev)[(b << 9) + c4]
                              : ((const float4*)x)[(size_t)gn * 512 - 512 + c4];
  const float4 k = ((const float4*)x_k)[c4];
  float hx = cur.x + (prv.x - cur.x) * k.x;
  float hy = cur.y + (prv.y - cur.y) * k.y;
  float hz = cur.z + (prv.z - cur.z) * k.z;
  float hw = cur.w + (prv.w - cur.w) * k.w;
  uint2 o;
  o.x = (unsigned int)f2bf(hx) | ((unsigned int)f2bf(hy) << 16);
  o.y = (unsigned int)f2bf(hz) | ((unsigned int)f2bf(hw) << 16);
  ((uint2*)h)[idx] = o;
}

__global__ __launch_bounds__(256) void xlast_kernel(
    const float* __restrict__ x, float* __restrict__ x_last) {
  const int i = blockIdx.x * 256 + threadIdx.x;
  const int b = i >> 9, c4 = i & 511;
  ((float4*)x_last)[i] =
      ((const float4*)x)[((size_t)b * 2048 + 2047) * 512 + c4];
}

__global__ __launch_bounds__(256) void transpose_cast(
    const float* __restrict__ in, unsigned short* __restrict__ outp,
    int rows, int cols) {
  __shared__ float tile[32][33];
  const int bx = blockIdx.x * 32, by = blockIdx.y * 32;
  const int tx = threadIdx.x, ty = threadIdx.y;
#pragma unroll
  for (int k = 0; k < 4; ++k)
    tile[ty + k * 8][tx] = in[(size_t)(by + ty + k * 8) * cols + bx + tx];
  __syncthreads();
#pragma unroll
  for (int k = 0; k < 4; ++k)
    outp[(size_t)(bx + ty + k * 8) * rows + by + tx] = f2bf(tile[tx][ty + k * 8]);
}

__global__ __launch_bounds__(256) void cast_bf16(
    const float* __restrict__ in, unsigned short* __restrict__ outp, int n4) {
  const int i = blockIdx.x * 256 + threadIdx.x;
  if (i >= n4) return;
  const float4 v = ((const float4*)in)[i];
  uint2 o;
  o.x = (unsigned int)f2bf(v.x) | ((unsigned int)f2bf(v.y) << 16);
  o.y = (unsigned int)f2bf(v.z) | ((unsigned int)f2bf(v.w) << 16);
  ((uint2*)outp)[i] = o;
}

// ---------------------------------------------------------------------------
__global__ __launch_bounds__(256) void router_kernel(
    const float* __restrict__ x, const float* __restrict__ x_prev,
    const float* __restrict__ x_k, const float* __restrict__ Rt,
    int* __restrict__ tbl, int* __restrict__ etok,
    float* __restrict__ gate_tok, int MC, int n0) {
  const int lane = threadIdx.x & 63, wid = threadIdx.x >> 6;
  const int nl = blockIdx.x * 4 + wid;
  const int gn = n0 + nl;
  const int t = gn & 2047, b = gn >> 11;
  const float* cur = x + (size_t)gn * 2048;
  const float* prv = (t == 0) ? x_prev + (size_t)b * 2048 : cur - 2048;
  float hv[32];
#pragma unroll
  for (int j = 0; j < 32; ++j) {
    const int i = j * 64 + lane;
    const float xc = cur[i];
    hv[j] = xc + (prv[i] - xc) * x_k[i];
  }
  float s[4];
  s[0] = 0.f;
  for (int e = 1; e < 4; ++e) {
    const float* rrow = Rt + (size_t)(e - 1) * 2048;
    float a = 0.f;
#pragma unroll
    for (int j = 0; j < 32; ++j) a += hv[j] * rrow[j * 64 + lane];
#pragma unroll
    for (int d = 32; d >= 1; d >>= 1) a += __shfl_xor(a, d, 64);
    s[e] = a;
  }
  if (lane == 0) {
    int i1 = 0; float v1 = s[0];
    for (int e = 1; e < 4; ++e) if (s[e] > v1) { v1 = s[e]; i1 = e; }
    int i2 = -1; float v2 = -1e30f;
    for (int e = 0; e < 4; ++e) if (e != i1 && s[e] > v2) { v2 = s[e]; i2 = e; }
    const float ex = expf(v2 - v1);
    const float g1 = 1.f / (1.f + ex), g2 = ex / (1.f + ex);
    etok[nl] = i1;          etok[MC + nl] = i2;
    gate_tok[nl] = g1;      gate_tok[MC + nl] = g2;
    atomicAdd(&tbl[i1], 1); atomicAdd(&tbl[4 + i2], 1);
  }
}

__global__ void zero_hist(int* tbl) {
  if (threadIdx.x < 8) tbl[threadIdx.x] = 0;
}

__global__ __launch_bounds__(128) void seg_build(int* __restrict__ tbl, int MB) {
  const int tid = threadIdx.x;
  __shared__ int sbase[2][5];
  if (tid == 0) {
    for (int k = 0; k < 2; ++k) {
      int b = 0; sbase[k][0] = 0;
      for (int e = 0; e < 4; ++e) {
        b += ((tbl[k * 4 + e] + 127) >> 7) << 7;
        sbase[k][e + 1] = b;
      }
      for (int e = 0; e < 5; ++e) tbl[16 + k * 5 + e] = sbase[k][e];
    }
    for (int i = 0; i < 8; ++i) tbl[8 + i] = 0;
  }
  __syncthreads();
  int* bt = tbl + 32;
  for (int i = tid; i < 2 * MB; i += 128) {
    const int k = i / MB, row = (i % MB) * 128;
    int e = -1;
    for (int q = 0; q < 4; ++q)
      if (row >= sbase[k][q] && row < sbase[k][q + 1]) e = q;
    bt[i] = e;
  }
  int* tok = tbl + 32 + 2 * MB;
  for (int i = tid; i < 2 * MB * 128; i += 128) tok[i] = -1;
}

__global__ __launch_bounds__(256) void scatter_build(
    int* __restrict__ tbl, const int* __restrict__ etok, int MC, int MB) {
  const int t = blockIdx.x * 256 + threadIdx.x;
  if (t >= MC) return;
  int* tok = tbl + 32 + 2 * MB;
#pragma unroll
  for (int k = 0; k < 2; ++k) {
    const int e = etok[k * MC + t];
    const int r = atomicAdd(&tbl[8 + k * 4 + e], 1);
    tok[k * MB * 128 + tbl[16 + k * 5 + e] + r] = t;
  }
}

// ---------------------------------------------------------------------------
// gemm256: 8-phase pipelined bf16 B^T GEMM. BM=256, BN=128, BK=64, 8 waves
// (wr=wid>>1 in 0..3, wc=wid&1). Wave tile 64x64, acc[4][4] f32x4.
// LDS: A [2 buf][mh(2)][wr(4)][32 rows][128B] (32KB/buf),
//      B [2 buf][nh(2)][wc(2)][32 rows][128B] (16KB/buf). XOR-swizzled.
// Phase (mh,nh): read 8 frags, stage per schedule, barrier, 8 MFMA, barrier.
// Stage: tile T+1 mh1/nh1 at T.p0; tile T+2 A-mh0 at T.p2, B-nh0 at T.p3.
// vmcnt(6) at ends of p0 and p3 (tail -> vmcnt(0)).
// ---------------------------------------------------------------------------
enum { EPI256_D = 0, EPI256_OUT = 1 };

#define GBAR asm volatile("s_barrier" ::: "memory")

template <int EPI>
__global__ __launch_bounds__(512, 1) void gemm256(
    const unsigned short* __restrict__ A, int lda,
    const unsigned short* __restrict__ Bt, int ldb,
    void* __restrict__ Cp, int ldc, int K, int nbx,
    const int* __restrict__ tok, const int* __restrict__ etok,
    const float* __restrict__ gtok, unsigned short* __restrict__ out2,
    unsigned short* __restrict__ vatp, int PRr, int MCr) {
  __shared__ alignas(16) char As_[2][32768];
  __shared__ alignas(16) char Bs_[2][16384];
  const int nwg = gridDim.x, wg = blockIdx.x;
  const int q = nwg >> 3, r = nwg & 7;
  const int xcd = wg & 7, loc = wg >> 3;
  const int swz = (xcd < r ? xcd * (q + 1) : r * (q + 1) + (xcd - r) * q) + loc;
  const int bx = swz % nbx, by = swz / nbx;
  const int m0 = by * 256, n0 = bx * 128;
  const int tid = threadIdx.x, lane = tid & 63;
  const int wid = tid >> 6, wr = wid >> 1, wc = wid & 1;

  // A half mh of K-tile kt -> buf (2 x 8KB loads)
  auto stageA = [&](int buf, int mh, int kt) {
#pragma unroll
    for (int j = 0; j < 2; ++j) {
      const int rh = j * 64 + (tid >> 3);     // 0..127 within half
      const int w = tid & 7;
      const int grow = m0 + (rh >> 5) * 64 + mh * 32 + (rh & 31);
      const unsigned short* src =
          A + (size_t)grow * lda + kt + ((w ^ (rh & 7)) * 8);
      __builtin_amdgcn_global_load_lds(
          (const __attribute__((address_space(1))) void*)src,
          (__attribute__((address_space(3))) void*)(
              &As_[buf][mh * 16384 + j * 8192 + tid * 16]), 16, 0, 0);
    }
  };
  // B half nh of K-tile kt -> buf (1 x 8KB load)
  auto stageB = [&](int buf, int nh, int kt) {
    const int rh = tid >> 3;                  // 0..63
    const int w = tid & 7;
    const int gcol = n0 + (rh >> 5) * 64 + nh * 32 + (rh & 31);
    const unsigned short* src =
        Bt + (size_t)gcol * ldb + kt + ((w ^ (rh & 7)) * 8);
    __builtin_amdgcn_global_load_lds(
        (const __attribute__((address_space(1))) void*)src,
        (__attribute__((address_space(3))) void*)(
            &Bs_[buf][nh * 8192 + tid * 16]), 16, 0, 0);
  };

  f32x4 acc[4][4] = {};
  const int NT = K >> 6;

  // prologue: tile0 full + tile1 (A-mh0, B-nh0); leave 6 in flight
  stageA(0, 0, 0); stageB(0, 0, 0);
  stageA(0, 1, 0); stageB(0, 1, 0);
  stageA(1, 0, 64); stageB(1, 0, 64);
  asm volatile("s_waitcnt vmcnt(6)" ::: "memory");
  GBAR;

#define READ_FRAGS(buf, mh, nh)                                              \
  bf16x8 af[2][2], bv[2][2];                                                 \
  _Pragma("unroll") for (int mi = 0; mi < 2; ++mi)                           \
  _Pragma("unroll") for (int ks = 0; ks < 2; ++ks) {                         \
    const int rp = (mh) * 128 + wr * 32 + mi * 16 + (lane & 15);             \
    af[mi][ks] = *(const bf16x8*)(&As_[buf][rp * 128 +                       \
        ((ks * 64 + ((lane >> 4) * 16)) ^ ((rp & 7) << 4))]);                \
  }                                                                          \
  _Pragma("unroll") for (int ni = 0; ni < 2; ++ni)                           \
  _Pragma("unroll") for (int ks = 0; ks < 2; ++ks) {                         \
    const int rp = (nh) * 64 + wc * 32 + ni * 16 + (lane & 15);              \
    bv[ni][ks] = *(const bf16x8*)(&Bs_[buf][rp * 128 +                       \
        ((ks * 64 + ((lane >> 4) * 16)) ^ ((rp & 7) << 4))]);                \
  }

#define DO_MFMA(mh, nh)                                                      \
  __builtin_amdgcn_s_setprio(1);                                             \
  _Pragma("unroll") for (int ks = 0; ks < 2; ++ks)                           \
  _Pragma("unroll") for (int mi = 0; mi < 2; ++mi)                           \
  _Pragma("unroll") for (int ni = 0; ni < 2; ++ni)                           \
    acc[(mh) * 2 + mi][(nh) * 2 + ni] =                                      \
        __builtin_amdgcn_mfma_f32_16x16x32_bf16(                             \
            af[mi][ks], bv[ni][ks], acc[(mh) * 2 + mi][(nh) * 2 + ni],       \
            0, 0, 0);                                                        \
  __builtin_amdgcn_s_setprio(0);

  for (int T = 0; T < NT; ++T) {
    const int buf = T & 1;
    { // p0 (mh0, nh0): stage tile T+1 mh1/nh1 into buf^1
      READ_FRAGS(buf, 0, 0);
      if (T + 1 < NT) { stageA(buf ^ 1, 1, (T + 1) << 6);
                        stageB(buf ^ 1, 1, (T + 1) << 6); }
      GBAR;
      DO_MFMA(0, 0);
      asm volatile("s_waitcnt vmcnt(6)" ::: "memory");
      GBAR;
    }
    { // p1 (mh0, nh1)
      READ_FRAGS(buf, 0, 1);
      GBAR;
      DO_MFMA(0, 1);
      GBAR;
    }
    { // p2 (mh1, nh0): stage tile T+2 A-mh0 into buf (A-mh0 free after p1)
      READ_FRAGS(buf, 1, 0);
      if (T + 2 < NT) stageA(buf, 0, (T + 2) << 6);
      GBAR;
      DO_MFMA(1, 0);
      GBAR;
    }
    { // p3 (mh1, nh1): stage tile T+2 B-nh0 into buf (B-nh0 free after p2)
      READ_FRAGS(buf, 1, 1);
      if (T + 2 < NT) stageB(buf, 0, (T + 2) << 6);
      GBAR;
      DO_MFMA(1, 1);
      if (T + 2 < NT) { asm volatile("s_waitcnt vmcnt(6)" ::: "memory"); }
      else            { asm volatile("s_waitcnt vmcnt(0)" ::: "memory"); }
      GBAR;
    }
  }
#undef READ_FRAGS
#undef DO_MFMA

  // epilogue: C/D layout col = lane&15, row = (lane>>4)*4 + j  [m89/m91]
  const int cc = lane & 15, cr0 = (lane >> 4) * 4;
#pragma unroll
  for (int m = 0; m < 4; ++m) {
#pragma unroll
    for (int n = 0; n < 4; ++n) {
#pragma unroll
      for (int j = 0; j < 4; ++j) {
        const int grow = m0 + wr * 64 + m * 16 + cr0 + j;
        const int lcol = wc * 64 + n * 16 + cc;      // 0..127
        const float v = acc[m][n][j];
        if constexpr (EPI == EPI256_D) {
          ((unsigned short*)Cp)[(size_t)grow * ldc + n0 + lcol] = f2bf(v);
        } else {
          const int t = tok[grow];
          if (t >= 0) {
            const int k = (grow >= PRr) ? 1 : 0;
            if (bx >= nbx - 2) {     // VaAll columns (2 n-blocks = 256 cols)
              const int vcol = (bx - (nbx - 2)) * 128 + lcol;  // 0..255
              if ((vcol >> 6) == etok[k * MCr + t])
                vatp[(size_t)grow * 64 + (vcol & 63)] = f2bf(v);
            } else {
              const float g = gtok[k * MCr + t];
              const int gc = n0 + lcol;
              if (k == 0) ((float*)Cp)[(size_t)t * ldc + gc] = g * v;
              else        out2[(size_t)t * ldc + gc] = f2bf(g * v);
            }
          }
        }
      }
    }
  }
}

// ---------------------------------------------------------------------------
// 128x128 B^T GEMM for the K=64 stages (memory-bound).
// EPI_KE:  k_e[k] = relu(aux[tok] + 2*acc)^2 bf16 (slot-merged, mbPerSlot=MB).
// EPI_VB0: out[t] += scale*gate[t]*acc (f32 RMW).
// EPI_VB1: out[t] += bf2f(out2[t]) + scale*gate[t]*acc.
// ---------------------------------------------------------------------------
enum { EPI_KE = 0, EPI_VB0 = 1, EPI_VB1 = 2 };

template <int EPI>
__global__ __launch_bounds__(256) void gemm_bt(
    const unsigned short* __restrict__ A, int lda, long long strideAe,
    const unsigned short* __restrict__ B, int ldb, long long strideBe,
    void* __restrict__ Cp, int ldc, long long strideCslot,
    const unsigned short* __restrict__ aux, int ldaux,
    const float* __restrict__ gate, const unsigned short* __restrict__ out2,
    float scale,
    const int* __restrict__ blocktab, const int* __restrict__ rowmap,
    const int* __restrict__ crowmap,
    int K, int nbx, int mbPerSlot, int PRr, int MCr) {
  constexpr int BM = 128, BN = 128, BK = 64;

  const int nwg = gridDim.x, wg = blockIdx.x;
  const int q = nwg >> 3, r = nwg & 7;
  const int xcd = wg & 7, loc = wg >> 3;
  const int swz = (xcd < r ? xcd * (q + 1) : r * (q + 1) + (xcd - r) * q) + loc;
  const int bx = swz % nbx;
  const int by = swz / nbx;

  int k = 0, byl = by;
  if (mbPerSlot > 0) { k = by / mbPerSlot; byl = by - k * mbPerSlot; }

  int e = 0;
  if (blocktab) { e = blocktab[by]; if (e < 0) return; }

  __shared__ alignas(16) char smem[(BM + BN) * BK * 2];
  char* As = smem;
  char* Bs = smem + BM * BK * 2;

  const unsigned short* Ae = A + (size_t)e * strideAe;

  const int tid = threadIdx.x;
  const int lane = tid & 63;
  const int wid = tid >> 6;
  const int wr = wid >> 1, wc = wid & 1;
  const int m0 = byl * BM;
  const int bn0 = bx * BN;

  const int* tokA = rowmap ? rowmap + k * PRr : nullptr;
  int arow[4];
#pragma unroll
  for (int i = 0; i < 4; ++i) {
    const int row = (i * 256 + tid) >> 3;
    int rr = m0 + row;
    if (tokA) { rr = tokA[rr]; if (rr < 0) rr = 0; }
    arow[i] = rr;
  }

  f32x4 acc[4][4] = {};

  for (int kt = 0; kt < K; kt += BK) {
    __syncthreads();
#pragma unroll
    for (int i = 0; i < 4; ++i) {
      const int qq = i * 256 + tid;
      const int row = qq >> 3, w = qq & 7;
      const int g = w ^ (row & 7);
      const unsigned short* src = Ae + (size_t)arow[i] * lda + kt + g * 8;
      __builtin_amdgcn_global_load_lds(
          (const __attribute__((address_space(1))) void*)src,
          (__attribute__((address_space(3))) void*)(As + qq * 16), 16, 0, 0);
    }
#pragma unroll
    for (int i = 0; i < 4; ++i) {
      const int qq = i * 256 + tid;
      const int row = qq >> 3, w = qq & 7;
      const int g = w ^ (row & 7);
      const unsigned short* src =
          B + (size_t)e * strideBe + (size_t)(bn0 + row) * ldb + kt + g * 8;
      __builtin_amdgcn_global_load_lds(
          (const __attribute__((address_space(1))) void*)src,
          (__attribute__((address_space(3))) void*)(Bs + qq * 16), 16, 0, 0);
    }
    asm volatile("s_waitcnt vmcnt(0)" ::: "memory");
    __syncthreads();

#pragma unroll
    for (int ks = 0; ks < 2; ++ks) {
      bf16x8 af[4], bfr[4];
#pragma unroll
      for (int m = 0; m < 4; ++m) {
        const int row = wr * 64 + m * 16 + (lane & 15);
        const int kb = (ks * 64 + ((lane >> 4) * 16)) ^ ((row & 7) << 4);
        af[m] = *(const bf16x8*)(As + row * 128 + kb);
      }
#pragma unroll
      for (int n = 0; n < 4; ++n) {
        const int row = wc * 64 + n * 16 + (lane & 15);
        const int kb = (ks * 64 + ((lane >> 4) * 16)) ^ ((row & 7) << 4);
        bfr[n] = *(const bf16x8*)(Bs + row * 128 + kb);
      }
#pragma unroll
      for (int m = 0; m < 4; ++m)
#pragma unroll
        for (int n = 0; n < 4; ++n)
          acc[m][n] = __builtin_amdgcn_mfma_f32_16x16x32_bf16(
              af[m], bfr[n], acc[m][n], 0, 0, 0);
    }
  }

  const int cc = lane & 15;
  const int cr0 = (lane >> 4) * 4;
#pragma unroll
  for (int m = 0; m < 4; ++m) {
#pragma unroll
    for (int n = 0; n < 4; ++n) {
#pragma unroll
      for (int j = 0; j < 4; ++j) {
        const int grow = m0 + wr * 64 + m * 16 + cr0 + j;
        const int lcol = wc * 64 + n * 16 + cc;
        const float v = acc[m][n][j];
        if constexpr (EPI == EPI_KE) {
          int ar = grow;
          if (tokA) { ar = tokA[grow]; if (ar < 0) ar = 0; }
          const float ksv = bf2f(aux[(size_t)ar * ldaux + bn0 + lcol]);
          float rr = ksv + 2.0f * v;  // LORA_SCALING = 2
          rr = rr > 0.f ? rr : 0.f;
          ((unsigned short*)Cp + (size_t)k * strideCslot)
              [(size_t)grow * ldc + bn0 + lcol] = f2bf(rr * rr);
        } else if constexpr (EPI == EPI_VB0) {
          const int t = crowmap[grow];
          if (t >= 0) {
            const float g = gate[t] * scale;
            float* o = (float*)Cp + (size_t)t * ldc + bn0 + lcol;
            *o = *o + g * v;
          }
        } else {  // EPI_VB1
          const int t = crowmap[grow];
          if (t >= 0) {
            const float g = gate[t] * scale;
            float* o = (float*)Cp + (size_t)t * ldc + bn0 + lcol;
            *o = *o + bf2f(out2[(size_t)t * ldc + bn0 + lcol]) + g * v;
          }
        }
      }
    }
  }
}

// ---------------------------------------------------------------------------
extern "C" void kernel_launch(void* const* d_in, const int* in_sizes, int n_in,
                              void* d_out, int out_size, void* d_ws,
                              size_t ws_size, hipStream_t stream) {
  (void)in_sizes; (void)n_in; (void)out_size;
  const float* x      = (const float*)d_in[0];
  const float* x_prev = (const float*)d_in[1];
  const float* x_k    = (const float*)d_in[2];
  const float* Router = (const float*)d_in[3];
  const float* K_ref  = (const float*)d_in[4];
  const float* V_ref  = (const float*)d_in[5];
  const float* Ka     = (const float*)d_in[6];
  const float* Kb     = (const float*)d_in[7];
  const float* Va     = (const float*)d_in[8];
  const float* Vb     = (const float*)d_in[9];

  constexpr int Bb = 4, T = 2048, C = 2048, H = 8192, R = 64, E = 4;
  constexpr int M = Bb * T;       // 8192 tokens
  constexpr int NKL = H + E * R;  // 8448 kshlora cols / KtKa rows
  constexpr int NVV = C + E * R;  // 2304 VtVa rows

  const size_t PAD = 255;
  auto rnd = [&](size_t b) { return (b + PAD) & ~PAD; };
  const size_t persist = rnd((size_t)NKL * C * 2)     // KtKa
                       + rnd((size_t)NVV * H * 2)     // VtVa
                       + rnd((size_t)E * H * R * 2)   // KbB
                       + rnd((size_t)E * C * R * 2);  // VbB

  // largest MC (pow2, mult of 256) fitting the aliased layout
  int MC = 0;
  for (int cand = M; cand >= 1024; cand >>= 1) {
    const int mb = cand / 128 + 4;
    const long long pr = (long long)mb * 128;
    const size_t span0 = rnd((size_t)2 * pr * H * 2);       // k_e  (>= h_c)
    const size_t span1 = rnd((size_t)cand * NKL * 2);       // kshlora (>= out2)
    const size_t rest = rnd((size_t)2 * pr * 64 * 2)        // vat
                      + rnd((size_t)(32 + 2 * mb + 2 * pr) * 4)
                      + rnd((size_t)2 * cand * 4) + rnd((size_t)2 * cand * 4);
    if (persist + span0 + span1 + rest <= ws_size) { MC = cand; break; }
  }
  if (MC == 0) return;
  const int MB = MC / 128 + 4;
  const int PR = MB * 128;

  char* ws = (char*)d_ws;
  size_t off = 0;
  auto alloc = [&](size_t bytes) -> char* {
    char* p = ws + off; off += rnd(bytes); return p;
  };
  unsigned short* KtKa = (unsigned short*)alloc((size_t)NKL * C * 2);
  unsigned short* VtVa = (unsigned short*)alloc((size_t)NVV * H * 2);
  unsigned short* KbB  = (unsigned short*)alloc((size_t)E * H * R * 2);
  unsigned short* VbB  = (unsigned short*)alloc((size_t)E * C * R * 2);
  unsigned short* k_e  = (unsigned short*)alloc((size_t)2 * PR * H * 2);
  unsigned short* ksl  = (unsigned short*)alloc((size_t)MC * NKL * 2);
  unsigned short* vat  = (unsigned short*)alloc((size_t)2 * PR * 64 * 2);
  int*            tbl  = (int*)alloc((size_t)(32 + 2 * MB + 2 * PR) * 4);
  int*            etok = (int*)alloc((size_t)2 * MC * 4);
  float*          gtok = (float*)alloc((size_t)2 * MC * 4);
  unsigned short* h_c  = k_e;             // alias: h dead after kshlora GEMM
  unsigned short* out2 = ksl;             // alias: kshlora dead after KE

  float* out    = (float*)d_out;
  float* x_last = out + (size_t)M * C;

  // ---- one-time: weights -> bf16 combined buffers ----
  transpose_cast<<<dim3(H / 32, C / 32), dim3(32, 8), 0, stream>>>(K_ref, KtKa, C, H);
  cast_bf16<<<(E * R * C / 4 + 255) / 256, 256, 0, stream>>>(
      Ka, KtKa + (size_t)H * C, E * R * C / 4);
  transpose_cast<<<dim3(C / 32, H / 32), dim3(32, 8), 0, stream>>>(V_ref, VtVa, H, C);
  cast_bf16<<<(E * R * H / 4 + 255) / 256, 256, 0, stream>>>(
      Va, VtVa + (size_t)C * H, E * R * H / 4);
  cast_bf16<<<(E * H * R / 4 + 255) / 256, 256, 0, stream>>>(Kb, KbB, E * H * R / 4);
  cast_bf16<<<(E * C * R / 4 + 255) / 256, 256, 0, stream>>>(Vb, VbB, E * C * R / 4);
  xlast_kernel<<<Bb * C / 4 / 256, 256, 0, stream>>>(x, x_last);

  // ---- per-chunk pipeline ----
  for (int c0 = 0; c0 < M; c0 += MC) {
    float* outc = out + (size_t)c0 * C;
    prep_kernel<<<MC * C / 4 / 256, 256, 0, stream>>>(x, x_prev, x_k, h_c, c0);
    zero_hist<<<1, 64, 0, stream>>>(tbl);
    router_kernel<<<MC / 4, 256, 0, stream>>>(x, x_prev, x_k, Router, tbl,
                                              etok, gtok, MC, c0);
    seg_build<<<1, 128, 0, stream>>>(tbl, MB);
    scatter_build<<<(MC + 255) / 256, 256, 0, stream>>>(tbl, etok, MC, MB);

    const int* bt  = tbl + 32;
    const int* tok = tbl + 32 + 2 * MB;

    // kshlora = h @ [K_ref^T ; KaAll]  [MC x 8448], K=C  (8-phase 256x128)
    gemm256<EPI256_D><<<(MC / 256) * (NKL / 128), 512, 0, stream>>>(
        h_c, C, KtKa, C, ksl, NKL, C, NKL / 128,
        nullptr, nullptr, nullptr, nullptr, nullptr, PR, MC);

    // k_e[k] = relu(ksh[tok] + 2*lora[tok,e] @ Kb[e]^T)^2 — both slots, K=R
    gemm_bt<EPI_KE><<<(H / 128) * 2 * MB, 256, 0, stream>>>(
        ksl + H, NKL, 64, KbB, R, (long long)H * R,
        k_e, H, (long long)PR * H, ksl, NKL, nullptr, nullptr, 0.f,
        bt, tok, nullptr, R, H / 128, MB, PR, MC);

    // out/out2/vat = scatter(g * (k_e @ [V_ref^T ; VaAll]))  K=H (8-phase)
    gemm256<EPI256_OUT><<<MB * (NVV / 128), 512, 0, stream>>>(
        k_e, H, VtVa, H, outc, C, H, NVV / 128,
        tok, etok, gtok, out2, vat, PR, MC);

    // out += 2*g0*(vat0 @ Vb[e]^T)   (slot 0)
    gemm_bt<EPI_VB0><<<(C / 128) * MB, 256, 0, stream>>>(
        vat, 64, 0, VbB, R, (long long)C * R,
        outc, C, 0, nullptr, 0, gtok, nullptr, 2.0f,
        bt, nullptr, tok, R, C / 128, 0, PR, MC);

    // out += out2 + 2*g1*(vat1 @ Vb[e]^T)   (slot 1)
    gemm_bt<EPI_VB1><<<(C / 128) * MB, 256, 0, stream>>>(
        vat + (size_t)PR * 64, 64, 0, VbB, R, (long long)C * R,
        outc, C, 0, nullptr, 0, gtok + MC, out2, 2.0f,
        bt + MB, nullptr, tok + PR, R, C / 128, 0, PR, MC);
  }
}

// Round 11
// 2510.899 us; speedup vs baseline: 1.3163x; 1.3163x over previous
//
#include <hip/hip_runtime.h>

// ---------------------------------------------------------------------------
// RWKV-7 MoE FFN, MI355X (gfx950). bf16 MFMA + top-2 sparse expert dispatch.
// r11: proven 128^2 gemm_bt everywhere; sequential slots; single k_e buffer
// (aliased with h_c) so MC=4096 fits ws; kshlora merged (KtKa concat);
// vat fused into GV as VtVa n-blocks 16..17; slot0 GV pure-write init,
// slot1 GV RMW. No schedule experiments — all pieces measured in r7/r8/r9.
// Shapes fixed: B=4 T=2048 C=2048 H=8192 R=64 E=4, topk=2.
// ---------------------------------------------------------------------------

#define DEV_INLINE __device__ __forceinline__

typedef __attribute__((ext_vector_type(8))) short bf16x8;
typedef __attribute__((ext_vector_type(4))) float f32x4;

DEV_INLINE unsigned short f2bf(float f) {
  union { float f; unsigned int u; } v; v.f = f;
  unsigned int u = v.u;
  unsigned int r = (u + 0x7FFFu + ((u >> 16) & 1u)) >> 16;  // RTNE
  return (unsigned short)r;
}
DEV_INLINE float bf2f(unsigned short s) {
  union { unsigned int u; float f; } v; v.u = ((unsigned int)s) << 16;
  return v.f;
}

// tbl ints: [0:8) hist[2][4], [8:16) fill[2][4], [16:26) base[2][5],
// [32:32+2*MB) blocktab[2][MB], [32+2*MB:...) tok[2][PR]

// ---------------------------------------------------------------------------
__global__ __launch_bounds__(256) void prep_kernel(
    const float* __restrict__ x, const float* __restrict__ x_prev,
    const float* __restrict__ x_k, unsigned short* __restrict__ h, int n0) {
  const int idx = blockIdx.x * 256 + threadIdx.x;
  const int c4 = idx & 511;
  const int gn = n0 + (idx >> 9);
  const int t  = gn & 2047;
  const int b  = gn >> 11;
  const float4 cur = ((const float4*)x)[(size_t)gn * 512 + c4];
  const float4 prv = (t == 0) ? ((const float4*)x_prev)[(b << 9) + c4]
                              : ((const float4*)x)[(size_t)gn * 512 - 512 + c4];
  const float4 k = ((const float4*)x_k)[c4];
  float hx = cur.x + (prv.x - cur.x) * k.x;
  float hy = cur.y + (prv.y - cur.y) * k.y;
  float hz = cur.z + (prv.z - cur.z) * k.z;
  float hw = cur.w + (prv.w - cur.w) * k.w;
  uint2 o;
  o.x = (unsigned int)f2bf(hx) | ((unsigned int)f2bf(hy) << 16);
  o.y = (unsigned int)f2bf(hz) | ((unsigned int)f2bf(hw) << 16);
  ((uint2*)h)[idx] = o;
}

__global__ __launch_bounds__(256) void xlast_kernel(
    const float* __restrict__ x, float* __restrict__ x_last) {
  const int i = blockIdx.x * 256 + threadIdx.x;
  const int b = i >> 9, c4 = i & 511;
  ((float4*)x_last)[i] =
      ((const float4*)x)[((size_t)b * 2048 + 2047) * 512 + c4];
}

__global__ __launch_bounds__(256) void transpose_cast(
    const float* __restrict__ in, unsigned short* __restrict__ outp,
    int rows, int cols) {
  __shared__ float tile[32][33];
  const int bx = blockIdx.x * 32, by = blockIdx.y * 32;
  const int tx = threadIdx.x, ty = threadIdx.y;
#pragma unroll
  for (int k = 0; k < 4; ++k)
    tile[ty + k * 8][tx] = in[(size_t)(by + ty + k * 8) * cols + bx + tx];
  __syncthreads();
#pragma unroll
  for (int k = 0; k < 4; ++k)
    outp[(size_t)(bx + ty + k * 8) * rows + by + tx] = f2bf(tile[tx][ty + k * 8]);
}

__global__ __launch_bounds__(256) void cast_bf16(
    const float* __restrict__ in, unsigned short* __restrict__ outp, int n4) {
  const int i = blockIdx.x * 256 + threadIdx.x;
  if (i >= n4) return;
  const float4 v = ((const float4*)in)[i];
  uint2 o;
  o.x = (unsigned int)f2bf(v.x) | ((unsigned int)f2bf(v.y) << 16);
  o.y = (unsigned int)f2bf(v.z) | ((unsigned int)f2bf(v.w) << 16);
  ((uint2*)outp)[i] = o;
}

// ---------------------------------------------------------------------------
__global__ __launch_bounds__(256) void router_kernel(
    const float* __restrict__ x, const float* __restrict__ x_prev,
    const float* __restrict__ x_k, const float* __restrict__ Rt,
    int* __restrict__ tbl, int* __restrict__ etok,
    float* __restrict__ gate_tok, int MC, int n0) {
  const int lane = threadIdx.x & 63, wid = threadIdx.x >> 6;
  const int nl = blockIdx.x * 4 + wid;
  const int gn = n0 + nl;
  const int t = gn & 2047, b = gn >> 11;
  const float* cur = x + (size_t)gn * 2048;
  const float* prv = (t == 0) ? x_prev + (size_t)b * 2048 : cur - 2048;
  float hv[32];
#pragma unroll
  for (int j = 0; j < 32; ++j) {
    const int i = j * 64 + lane;
    const float xc = cur[i];
    hv[j] = xc + (prv[i] - xc) * x_k[i];
  }
  float s[4];
  s[0] = 0.f;
  for (int e = 1; e < 4; ++e) {
    const float* rrow = Rt + (size_t)(e - 1) * 2048;
    float a = 0.f;
#pragma unroll
    for (int j = 0; j < 32; ++j) a += hv[j] * rrow[j * 64 + lane];
#pragma unroll
    for (int d = 32; d >= 1; d >>= 1) a += __shfl_xor(a, d, 64);
    s[e] = a;
  }
  if (lane == 0) {
    int i1 = 0; float v1 = s[0];
    for (int e = 1; e < 4; ++e) if (s[e] > v1) { v1 = s[e]; i1 = e; }
    int i2 = -1; float v2 = -1e30f;
    for (int e = 0; e < 4; ++e) if (e != i1 && s[e] > v2) { v2 = s[e]; i2 = e; }
    const float ex = expf(v2 - v1);
    const float g1 = 1.f / (1.f + ex), g2 = ex / (1.f + ex);
    etok[nl] = i1;          etok[MC + nl] = i2;
    gate_tok[nl] = g1;      gate_tok[MC + nl] = g2;
    atomicAdd(&tbl[i1], 1); atomicAdd(&tbl[4 + i2], 1);
  }
}

__global__ void zero_hist(int* tbl) {
  if (threadIdx.x < 8) tbl[threadIdx.x] = 0;
}

__global__ __launch_bounds__(128) void seg_build(int* __restrict__ tbl, int MB) {
  const int tid = threadIdx.x;
  __shared__ int sbase[2][5];
  if (tid == 0) {
    for (int k = 0; k < 2; ++k) {
      int b = 0; sbase[k][0] = 0;
      for (int e = 0; e < 4; ++e) {
        b += ((tbl[k * 4 + e] + 127) >> 7) << 7;
        sbase[k][e + 1] = b;
      }
      for (int e = 0; e < 5; ++e) tbl[16 + k * 5 + e] = sbase[k][e];
    }
    for (int i = 0; i < 8; ++i) tbl[8 + i] = 0;
  }
  __syncthreads();
  int* bt = tbl + 32;
  for (int i = tid; i < 2 * MB; i += 128) {
    const int k = i / MB, row = (i % MB) * 128;
    int e = -1;
    for (int q = 0; q < 4; ++q)
      if (row >= sbase[k][q] && row < sbase[k][q + 1]) e = q;
    bt[i] = e;
  }
  int* tok = tbl + 32 + 2 * MB;
  for (int i = tid; i < 2 * MB * 128; i += 128) tok[i] = -1;
}

__global__ __launch_bounds__(256) void scatter_build(
    int* __restrict__ tbl, const int* __restrict__ etok, int MC, int MB) {
  const int t = blockIdx.x * 256 + threadIdx.x;
  if (t >= MC) return;
  int* tok = tbl + 32 + 2 * MB;
#pragma unroll
  for (int k = 0; k < 2; ++k) {
    const int e = etok[k * MC + t];
    const int r = atomicAdd(&tbl[8 + k * 4 + e], 1);
    tok[k * MB * 128 + tbl[16 + k * 5 + e] + r] = t;
  }
}

// ---------------------------------------------------------------------------
// 128x128xBK=64 B^T GEMM (m97-class, measured 650-860 TF in r7/r8), with
// XCD-bijective swizzle, optional expert blocktab / A-row gather / C scatter.
// EPI_D:  dense bf16 store (kshlora).
// EPI_KE: k_e = relu(aux[tok] + 2*acc)^2 bf16.
// EPI_GV: n-blocks 0..15: out[t] (initC ? = : +=) gate[t]*acc (f32);
//         n-blocks 16..17 (VaAll cols 2048..2303): vat[grow][vcol&63] = bf16
//         iff (vcol>>6)==etokS[t].
// EPI_VB: out[t] += scale*gate[t]*acc (f32 RMW).
// ---------------------------------------------------------------------------
enum { EPI_D = 0, EPI_KE = 1, EPI_GV = 2, EPI_VB = 3 };

template <int EPI>
__global__ __launch_bounds__(256) void gemm_bt(
    const unsigned short* __restrict__ A, int lda, long long strideAe,
    const unsigned short* __restrict__ B, int ldb, long long strideBe,
    void* __restrict__ Cp, int ldc,
    const unsigned short* __restrict__ aux, int ldaux,
    const float* __restrict__ gate, const int* __restrict__ etokS,
    unsigned short* __restrict__ vatp, float scale, int initC,
    const int* __restrict__ blocktab, const int* __restrict__ rowmap,
    const int* __restrict__ crowmap, int K, int nbx) {
  constexpr int BM = 128, BN = 128, BK = 64;

  const int nwg = gridDim.x, wg = blockIdx.x;
  const int q = nwg >> 3, r = nwg & 7;
  const int xcd = wg & 7, loc = wg >> 3;
  const int swz = (xcd < r ? xcd * (q + 1) : r * (q + 1) + (xcd - r) * q) + loc;
  const int bx = swz % nbx;
  const int by = swz / nbx;

  int e = 0;
  if (blocktab) { e = blocktab[by]; if (e < 0) return; }

  __shared__ alignas(16) char smem[(BM + BN) * BK * 2];
  char* As = smem;
  char* Bs = smem + BM * BK * 2;

  const unsigned short* Ae = A + (size_t)e * strideAe;
  const unsigned short* Be = B + (size_t)e * strideBe;

  const int tid = threadIdx.x;
  const int lane = tid & 63;
  const int wid = tid >> 6;
  const int wr = wid >> 1, wc = wid & 1;
  const int m0 = by * BM;
  const int bn0 = bx * BN;

  int arow[4];
#pragma unroll
  for (int i = 0; i < 4; ++i) {
    const int row = (i * 256 + tid) >> 3;
    int rr = m0 + row;
    if (rowmap) { rr = rowmap[rr]; if (rr < 0) rr = 0; }
    arow[i] = rr;
  }

  f32x4 acc[4][4] = {};

  for (int kt = 0; kt < K; kt += BK) {
    __syncthreads();
#pragma unroll
    for (int i = 0; i < 4; ++i) {
      const int qq = i * 256 + tid;
      const int row = qq >> 3, w = qq & 7;
      const int g = w ^ (row & 7);
      const unsigned short* src = Ae + (size_t)arow[i] * lda + kt + g * 8;
      __builtin_amdgcn_global_load_lds(
          (const __attribute__((address_space(1))) void*)src,
          (__attribute__((address_space(3))) void*)(As + qq * 16), 16, 0, 0);
    }
#pragma unroll
    for (int i = 0; i < 4; ++i) {
      const int qq = i * 256 + tid;
      const int row = qq >> 3, w = qq & 7;
      const int g = w ^ (row & 7);
      const unsigned short* src = Be + (size_t)(bn0 + row) * ldb + kt + g * 8;
      __builtin_amdgcn_global_load_lds(
          (const __attribute__((address_space(1))) void*)src,
          (__attribute__((address_space(3))) void*)(Bs + qq * 16), 16, 0, 0);
    }
    asm volatile("s_waitcnt vmcnt(0)" ::: "memory");
    __syncthreads();

#pragma unroll
    for (int ks = 0; ks < 2; ++ks) {
      bf16x8 af[4], bfr[4];
#pragma unroll
      for (int m = 0; m < 4; ++m) {
        const int row = wr * 64 + m * 16 + (lane & 15);
        const int kb = (ks * 64 + ((lane >> 4) * 16)) ^ ((row & 7) << 4);
        af[m] = *(const bf16x8*)(As + row * 128 + kb);
      }
#pragma unroll
      for (int n = 0; n < 4; ++n) {
        const int row = wc * 64 + n * 16 + (lane & 15);
        const int kb = (ks * 64 + ((lane >> 4) * 16)) ^ ((row & 7) << 4);
        bfr[n] = *(const bf16x8*)(Bs + row * 128 + kb);
      }
#pragma unroll
      for (int m = 0; m < 4; ++m)
#pragma unroll
        for (int n = 0; n < 4; ++n)
          acc[m][n] = __builtin_amdgcn_mfma_f32_16x16x32_bf16(
              af[m], bfr[n], acc[m][n], 0, 0, 0);
    }
  }

  // epilogue: C/D layout col = lane&15, row = (lane>>4)*4 + j  [m89/m91]
  const int cc = lane & 15;
  const int cr0 = (lane >> 4) * 4;
#pragma unroll
  for (int m = 0; m < 4; ++m) {
#pragma unroll
    for (int n = 0; n < 4; ++n) {
#pragma unroll
      for (int j = 0; j < 4; ++j) {
        const int grow = m0 + wr * 64 + m * 16 + cr0 + j;
        const int lcol = wc * 64 + n * 16 + cc;
        const float v = acc[m][n][j];
        if constexpr (EPI == EPI_D) {
          ((unsigned short*)Cp)[(size_t)grow * ldc + bn0 + lcol] = f2bf(v);
        } else if constexpr (EPI == EPI_KE) {
          int ar = grow;
          if (rowmap) { ar = rowmap[grow]; if (ar < 0) ar = 0; }
          const float ksv = bf2f(aux[(size_t)ar * ldaux + bn0 + lcol]);
          float rr = ksv + 2.0f * v;  // LORA_SCALING = 2
          rr = rr > 0.f ? rr : 0.f;
          ((unsigned short*)Cp)[(size_t)grow * ldc + bn0 + lcol] =
              f2bf(rr * rr);
        } else if constexpr (EPI == EPI_GV) {
          const int t = crowmap[grow];
          if (t >= 0) {
            if (bn0 >= 2048) {                       // VaAll columns
              const int vcol = bn0 - 2048 + lcol;    // 0..255
              if ((vcol >> 6) == etokS[t])
                vatp[(size_t)grow * 64 + (vcol & 63)] = f2bf(v);
            } else {
              const float g = gate[t];
              float* o = (float*)Cp + (size_t)t * ldc + bn0 + lcol;
              *o = initC ? (g * v) : (*o + g * v);
            }
          }
        } else {  // EPI_VB
          const int t = crowmap[grow];
          if (t >= 0) {
            const float g = gate[t] * scale;
            float* o = (float*)Cp + (size_t)t * ldc + bn0 + lcol;
            *o = *o + g * v;
          }
        }
      }
    }
  }
}

// ---------------------------------------------------------------------------
extern "C" void kernel_launch(void* const* d_in, const int* in_sizes, int n_in,
                              void* d_out, int out_size, void* d_ws,
                              size_t ws_size, hipStream_t stream) {
  (void)in_sizes; (void)n_in; (void)out_size;
  const float* x      = (const float*)d_in[0];
  const float* x_prev = (const float*)d_in[1];
  const float* x_k    = (const float*)d_in[2];
  const float* Router = (const float*)d_in[3];
  const float* K_ref  = (const float*)d_in[4];
  const float* V_ref  = (const float*)d_in[5];
  const float* Ka     = (const float*)d_in[6];
  const float* Kb     = (const float*)d_in[7];
  const float* Va     = (const float*)d_in[8];
  const float* Vb     = (const float*)d_in[9];

  constexpr int Bb = 4, T = 2048, C = 2048, H = 8192, R = 64, E = 4;
  constexpr int M = Bb * T;       // 8192 tokens
  constexpr int NKL = H + E * R;  // 8448 kshlora cols / KtKa rows
  constexpr int NVV = C + E * R;  // 2304 VtVa rows (V_ref^T ; VaAll)

  const size_t PAD = 255;
  auto rnd = [&](size_t b) { return (b + PAD) & ~PAD; };
  const size_t persist = rnd((size_t)NKL * C * 2)     // KtKa
                       + rnd((size_t)NVV * H * 2)     // VtVa
                       + rnd((size_t)E * H * R * 2)   // KbB
                       + rnd((size_t)E * C * R * 2);  // VbB

  // largest MC (pow2 mult of 128) fitting: k_e span (aliases h_c) + ksl + misc
  int MC = 0;
  for (int cand = M; cand >= 1024; cand >>= 1) {
    const int mb = cand / 128 + 4;
    const long long pr = (long long)mb * 128;
    const size_t need = persist
                      + rnd((size_t)pr * H * 2)          // k_e (>= h_c 16MB)
                      + rnd((size_t)cand * NKL * 2)      // ksl
                      + rnd((size_t)pr * 64 * 2)         // vat
                      + rnd((size_t)(32 + 2 * mb + 2 * pr) * 4)
                      + rnd((size_t)2 * cand * 4)        // etok
                      + rnd((size_t)2 * cand * 4);       // gtok
    if (need <= ws_size) { MC = cand; break; }
  }
  if (MC == 0) return;
  const int MB = MC / 128 + 4;
  const int PR = MB * 128;

  char* ws = (char*)d_ws;
  size_t off = 0;
  auto alloc = [&](size_t bytes) -> char* {
    char* p = ws + off; off += rnd(bytes); return p;
  };
  unsigned short* KtKa = (unsigned short*)alloc((size_t)NKL * C * 2);
  unsigned short* VtVa = (unsigned short*)alloc((size_t)NVV * H * 2);
  unsigned short* KbB  = (unsigned short*)alloc((size_t)E * H * R * 2);
  unsigned short* VbB  = (unsigned short*)alloc((size_t)E * C * R * 2);
  unsigned short* k_e  = (unsigned short*)alloc((size_t)PR * H * 2);
  unsigned short* ksl  = (unsigned short*)alloc((size_t)MC * NKL * 2);
  unsigned short* vat  = (unsigned short*)alloc((size_t)PR * 64 * 2);
  int*            tbl  = (int*)alloc((size_t)(32 + 2 * MB + 2 * PR) * 4);
  int*            etok = (int*)alloc((size_t)2 * MC * 4);
  float*          gtok = (float*)alloc((size_t)2 * MC * 4);
  unsigned short* h_c  = k_e;   // alias: h dead after kshlora GEMM

  float* out    = (float*)d_out;
  float* x_last = out + (size_t)M * C;

  // ---- one-time: weights -> bf16 combined buffers ----
  transpose_cast<<<dim3(H / 32, C / 32), dim3(32, 8), 0, stream>>>(K_ref, KtKa, C, H);
  cast_bf16<<<(E * R * C / 4 + 255) / 256, 256, 0, stream>>>(
      Ka, KtKa + (size_t)H * C, E * R * C / 4);
  transpose_cast<<<dim3(C / 32, H / 32), dim3(32, 8), 0, stream>>>(V_ref, VtVa, H, C);
  cast_bf16<<<(E * R * H / 4 + 255) / 256, 256, 0, stream>>>(
      Va, VtVa + (size_t)C * H, E * R * H / 4);
  cast_bf16<<<(E * H * R / 4 + 255) / 256, 256, 0, stream>>>(Kb, KbB, E * H * R / 4);
  cast_bf16<<<(E * C * R / 4 + 255) / 256, 256, 0, stream>>>(Vb, VbB, E * C * R / 4);
  xlast_kernel<<<Bb * C / 4 / 256, 256, 0, stream>>>(x, x_last);

  // ---- per-chunk pipeline ----
  for (int c0 = 0; c0 < M; c0 += MC) {
    float* outc = out + (size_t)c0 * C;
    prep_kernel<<<MC * C / 4 / 256, 256, 0, stream>>>(x, x_prev, x_k, h_c, c0);
    zero_hist<<<1, 64, 0, stream>>>(tbl);
    router_kernel<<<MC / 4, 256, 0, stream>>>(x, x_prev, x_k, Router, tbl,
                                              etok, gtok, MC, c0);
    seg_build<<<1, 128, 0, stream>>>(tbl, MB);
    scatter_build<<<(MC + 255) / 256, 256, 0, stream>>>(tbl, etok, MC, MB);

    // kshlora = h @ [K_ref^T ; KaAll]  [MC x 8448], K=C (dense)
    gemm_bt<EPI_D><<<(NKL / 128) * (MC / 128), 256, 0, stream>>>(
        h_c, C, 0, KtKa, C, 0, ksl, NKL, nullptr, 0,
        nullptr, nullptr, nullptr, 0.f, 0,
        nullptr, nullptr, nullptr, C, NKL / 128);

    for (int k = 0; k < 2; ++k) {
      const int* bt   = tbl + 32 + k * MB;
      const int* tokk = tbl + 32 + 2 * MB + k * PR;
      const int* ek   = etok + (size_t)k * MC;
      const float* gk = gtok + (size_t)k * MC;

      // k_e = relu(ksh[tok] + 2 * lora[tok,e] @ Kb[e]^T)^2  [PR x H], K=R
      gemm_bt<EPI_KE><<<(H / 128) * MB, 256, 0, stream>>>(
          ksl + H, NKL, 64, KbB, R, (long long)H * R, k_e, H, ksl, NKL,
          nullptr, nullptr, nullptr, 0.f, 0,
          bt, tokk, nullptr, R, H / 128);

      // out[t] (init/RMW) g*(k_e @ V_ref^T); vat via VaAll n-blocks. K=H
      gemm_bt<EPI_GV><<<(NVV / 128) * MB, 256, 0, stream>>>(
          k_e, H, 0, VtVa, H, 0, outc, C, nullptr, 0,
          gk, ek, vat, 1.0f, (k == 0) ? 1 : 0,
          bt, nullptr, tokk, H, NVV / 128);

      // out[t] += 2*g*(vat @ Vb[e]^T)  [PR x C], K=R
      gemm_bt<EPI_VB><<<(C / 128) * MB, 256, 0, stream>>>(
          vat, 64, 0, VbB, R, (long long)C * R, outc, C, nullptr, 0,
          gk, nullptr, nullptr, 2.0f, 0,
          bt, nullptr, tokk, R, C / 128);
    }
  }
}